// Round 1
// 295.173 us; speedup vs baseline: 1.0216x; 1.0216x over previous
//
#include <hip/hip_runtime.h>
#include <hip/hip_bf16.h>

#define T_DIM   64
#define IN_DIM  4096
#define OUT_DIM 12288
#define NGROUP  32      // IN/GS
#define R_DIM   16
#define LR      64      // L*R

#define BN 16           // out-cols per block -> grid = 12288/16 = 768 (3 blocks/CU)
#define BK2 256         // k per LDS stage (2 quant groups) -> 16 stages, 18 barriers total
#define NSTAGE (IN_DIM / BK2)    // 16
#define W_STRIDE (BK2 + 8)       // 264: row stride 132 dwords == 4 banks mod 32 -> uniform b128 reads
#define T_STRIDE (LR + 8)        // 72

#define KSPLIT 8
#define KSLICE (IN_DIM / KSPLIT)   // 512

// ws layout: [0,128KB) lora partials fp32 [KSPLIT][64][64];
//            [128KB, 128KB+512KB) x in bf16, MFMA A-FRAGMENT-MAJOR:
//            frag(rt,kb,lane) at ((rt*128+kb)*64+lane)*8 holds
//            x[rt*16 + (lane&15)][kb*32 + (lane>>4)*8 + 0..7]
#define PART_FLOATS (KSPLIT * T_DIM * LR)      // 32768 floats = 128 KiB
#define XBF_BYTE_OFF (PART_FLOATS * 4)

typedef __bf16 bf16x4 __attribute__((ext_vector_type(4)));
typedef __bf16 bf16x8 __attribute__((ext_vector_type(8)));
typedef float  f32x4  __attribute__((ext_vector_type(4)));

// Workgroup barrier that waits ONLY lgkmcnt(0) (LDS writes visible) and leaves
// global loads (vmcnt) IN FLIGHT. Legal here: all LDS staging data is produced
// by VALU from registers; global-load results get compiler-inserted per-use
// vmcnt waits. imm 0xC07F = vmcnt 63 (bits 3:0=0xF, 15:14=3), expcnt 7, lgkmcnt 0.
__device__ __forceinline__ void barrier_lgkm() {
    asm volatile("" ::: "memory");
    __builtin_amdgcn_s_waitcnt(0xC07F);
    __builtin_amdgcn_s_barrier();
    asm volatile("" ::: "memory");
}

// ---------------------------------------------------------------------------
// Kernel 1 (prep): blocks 0..127 convert x -> bf16 in A-fragment-major layout
// (2x parallelism vs previous 64 to halve the serialized conversion latency);
// blocks 128..639 compute K-split LoRA-down partials
// part[ks][t][c] = ls_c * dot(x[t,slice], down[c,slice])
// ---------------------------------------------------------------------------
__global__ __launch_bounds__(256) void prep_kernel(
    const float* __restrict__ x, const float* __restrict__ down,
    const float* __restrict__ lora_scales, float* __restrict__ part,
    __bf16* __restrict__ xbf2)
{
    const int tid = threadIdx.x;
    const int bid = blockIdx.x;

    if (bid < 128) {
        const int rt = bid & 3;
        const int kb = (bid >> 2) * 4 + (tid >> 6);   // wave w handles one frag column-block
        const int lane = tid & 63;
        const int row  = rt * 16 + (lane & 15);
        const int col0 = kb * 32 + (lane >> 4) * 8;
        float4 v0 = *(const float4*)(x + row * IN_DIM + col0);
        float4 v1 = *(const float4*)(x + row * IN_DIM + col0 + 4);
        bf16x8 b;
        b[0] = (__bf16)v0.x; b[1] = (__bf16)v0.y;
        b[2] = (__bf16)v0.z; b[3] = (__bf16)v0.w;
        b[4] = (__bf16)v1.x; b[5] = (__bf16)v1.y;
        b[6] = (__bf16)v1.z; b[7] = (__bf16)v1.w;
        *(bf16x8*)(xbf2 + ((rt * 128 + kb) * 64 + lane) * 8) = b;
        return;
    }

    __shared__ float d_lds[KSLICE];
    const int p  = bid - 128;
    const int c  = p & 63;
    const int ks = p >> 6;
    const float* dsl = down + c * IN_DIM + ks * KSLICE;
    for (int j = tid; j < KSLICE / 4; j += 256)
        ((float4*)d_lds)[j] = ((const float4*)dsl)[j];
    __syncthreads();
    const float ls = lora_scales[c >> 4];
    const int wave = tid >> 6, lane = tid & 63;
    for (int t = wave * 2; t < T_DIM; t += 8) {
        const float4* xr0 = (const float4*)(x + t * IN_DIM + ks * KSLICE);
        const float4* xr1 = (const float4*)(x + (t + 1) * IN_DIM + ks * KSLICE);
        float sa = 0.f, sb = 0.f;
#pragma unroll
        for (int j = 0; j < 2; ++j) {
            float4 dv = ((const float4*)d_lds)[lane + j * 64];
            float4 xa = xr0[lane + j * 64];
            float4 xb = xr1[lane + j * 64];
            sa += xa.x * dv.x + xa.y * dv.y + xa.z * dv.z + xa.w * dv.w;
            sb += xb.x * dv.x + xb.y * dv.y + xb.z * dv.z + xb.w * dv.w;
        }
        for (int off = 32; off; off >>= 1) {
            sa += __shfl_down(sa, off);
            sb += __shfl_down(sb, off);
        }
        if (lane == 0) {
            part[(ks * T_DIM + t) * LR + c]     = sa * ls;
            part[(ks * T_DIM + t + 1) * LR + c] = sb * ls;
        }
    }
}

// ---------------------------------------------------------------------------
// Kernel 2: y = x @ dequant(qW)^T + t @ up'^T
//   64x16 tile/block (grid 768, 3/CU). A-frags direct from L2-resident
//   frag-major xbf2; only dequantized w double-buffers through LDS.
//   R1 change: BK2=256 stages (2 groups per buffer) -> 18 barriers vs 33,
//   4x int4 q-loads/thread (64B in flight, one contiguous 1KB row per wave),
//   q refill issued 2 stages (~9k cyc) ahead of use. Barriers are lgkm-only
//   (see barrier_lgkm) so the q/A register pipeline stays in flight.
//   Accumulation order over chunks 0..31 identical to previous version.
// ---------------------------------------------------------------------------
__global__ __launch_bounds__(256, 3) void awq_lora_gemm_kernel(
    const __bf16* __restrict__ xbf2, const int* __restrict__ qweight,
    const int* __restrict__ zeros, const float* __restrict__ scales,
    const float* __restrict__ up, const float* __restrict__ part,
    float* __restrict__ out)
{
    __shared__ __bf16 w_lds[2][BN][W_STRIDE];   // 16896 B
    __shared__ __bf16 t_lds[T_DIM][T_STRIDE];   // 9216 B (tail only)
    __shared__ float  s_lds[BN][NGROUP];        // 2048 B
    __shared__ float  zs_lds[BN][NGROUP];       // 2048 B

    const int tid  = threadIdx.x;
    const int n0   = blockIdx.x * BN;
    const int wave = tid >> 6, lane = tid & 63;
    const int lrow = lane & 15, quad = lane >> 4;

    // q staging geometry: 16 rows x 256 ints per stage = 4 x int4 / thread.
    // For fixed it, a wave covers one contiguous 1KB row segment.
    int qrow[4], qcol[4], qoff[4];
#pragma unroll
    for (int it = 0; it < 4; ++it) {
        int e = (it * 256 + tid) * 4;
        qrow[it] = e >> 8; qcol[it] = e & 255;
        qoff[it] = (n0 + qrow[it]) * IN_DIM + qcol[it];
    }
    const int ghalf = qcol[0] >> 7;   // same for all it (it*1024 == 0 mod 256)

    // A geometry: frag(rt=wave, kb, lane) -> elem offset
    const __bf16* abase = xbf2 + wave * 65536 + lane * 8;

    // stage scales / (-zero*scale) FIRST so their vmcnt waits don't drain the
    // q/A prologue loads issued below: 16 rows x 32 groups
#pragma unroll
    for (int it = 0; it < 2; ++it) {
        int idx = it * 256 + tid;
        int row = idx >> 5, g = idx & 31;
        float s = scales[(n0 + row) * NGROUP + g];
        float z = (float)zeros[(n0 + row) * NGROUP + g];
        s_lds[row][g]  = s;
        zs_lds[row][g] = -z * s;
    }

    // prologue: q for stages 0,1; A-frags for chunks 0,1
    int4   qa[4], qb[4];
    bf16x8 arE[4], arO[4];
#pragma unroll
    for (int it = 0; it < 4; ++it) qa[it] = *(const int4*)(qweight + qoff[it]);
#pragma unroll
    for (int kk = 0; kk < 4; ++kk) arE[kk] = *(const bf16x8*)(abase + kk * 512);
#pragma unroll
    for (int it = 0; it < 4; ++it) qb[it] = *(const int4*)(qweight + qoff[it] + BK2);
#pragma unroll
    for (int kk = 0; kk < 4; ++kk) arO[kk] = *(const bf16x8*)(abase + 2048 + kk * 512);

    f32x4 acc = {0.f, 0.f, 0.f, 0.f};

    barrier_lgkm();   // s_lds / zs_lds ready; prologue loads stay in flight

    for (int s = 0; s < NSTAGE; s += 2) {
        // ---- stage s -> buf 0 (chunks 2s, 2s+1) ----
        {
            const int g0 = s * 2 + ghalf;
#pragma unroll
            for (int it = 0; it < 4; ++it) {
                const float sc = s_lds[qrow[it]][g0];
                const float zs = zs_lds[qrow[it]][g0];
                bf16x4 w;
                w[0] = (__bf16)((float)qa[it].x * sc + zs);
                w[1] = (__bf16)((float)qa[it].y * sc + zs);
                w[2] = (__bf16)((float)qa[it].z * sc + zs);
                w[3] = (__bf16)((float)qa[it].w * sc + zs);
                *(bf16x4*)&w_lds[0][qrow[it]][qcol[it]] = w;
            }
        }
        // qa consumed -> refill NOW for stage s+2 (2-stage DRAM lead)
        if (s + 2 < NSTAGE) {
            const int k0 = (s + 2) * BK2;
#pragma unroll
            for (int it = 0; it < 4; ++it) qa[it] = *(const int4*)(qweight + qoff[it] + k0);
        }
        barrier_lgkm();
#pragma unroll
        for (int kk = 0; kk < 4; ++kk) {                 // chunk 2s
            const int ko = kk * 32 + quad * 8;
            bf16x8 b0 = *(const bf16x8*)&w_lds[0][lrow][ko];
            acc = __builtin_amdgcn_mfma_f32_16x16x32_bf16(arE[kk], b0, acc, 0, 0, 0);
        }
#pragma unroll
        for (int kk = 0; kk < 4; ++kk) arE[kk] = *(const bf16x8*)(abase + (2*s + 2) * 2048 + kk * 512);
#pragma unroll
        for (int kk = 0; kk < 4; ++kk) {                 // chunk 2s+1
            const int ko = 128 + kk * 32 + quad * 8;
            bf16x8 b0 = *(const bf16x8*)&w_lds[0][lrow][ko];
            acc = __builtin_amdgcn_mfma_f32_16x16x32_bf16(arO[kk], b0, acc, 0, 0, 0);
        }
#pragma unroll
        for (int kk = 0; kk < 4; ++kk) arO[kk] = *(const bf16x8*)(abase + (2*s + 3) * 2048 + kk * 512);

        // ---- stage s+1 -> buf 1 (chunks 2s+2, 2s+3) ----
        {
            const int g0 = s * 2 + 2 + ghalf;
#pragma unroll
            for (int it = 0; it < 4; ++it) {
                const float sc = s_lds[qrow[it]][g0];
                const float zs = zs_lds[qrow[it]][g0];
                bf16x4 w;
                w[0] = (__bf16)((float)qb[it].x * sc + zs);
                w[1] = (__bf16)((float)qb[it].y * sc + zs);
                w[2] = (__bf16)((float)qb[it].z * sc + zs);
                w[3] = (__bf16)((float)qb[it].w * sc + zs);
                *(bf16x4*)&w_lds[1][qrow[it]][qcol[it]] = w;
            }
        }
        if (s + 3 < NSTAGE) {
            const int k0 = (s + 3) * BK2;
#pragma unroll
            for (int it = 0; it < 4; ++it) qb[it] = *(const int4*)(qweight + qoff[it] + k0);
        }
        barrier_lgkm();
#pragma unroll
        for (int kk = 0; kk < 4; ++kk) {                 // chunk 2s+2
            const int ko = kk * 32 + quad * 8;
            bf16x8 b0 = *(const bf16x8*)&w_lds[1][lrow][ko];
            acc = __builtin_amdgcn_mfma_f32_16x16x32_bf16(arE[kk], b0, acc, 0, 0, 0);
        }
        if (s + 2 < NSTAGE) {
#pragma unroll
            for (int kk = 0; kk < 4; ++kk) arE[kk] = *(const bf16x8*)(abase + (2*s + 4) * 2048 + kk * 512);
        }
#pragma unroll
        for (int kk = 0; kk < 4; ++kk) {                 // chunk 2s+3
            const int ko = 128 + kk * 32 + quad * 8;
            bf16x8 b0 = *(const bf16x8*)&w_lds[1][lrow][ko];
            acc = __builtin_amdgcn_mfma_f32_16x16x32_bf16(arO[kk], b0, acc, 0, 0, 0);
        }
        if (s + 2 < NSTAGE) {
#pragma unroll
            for (int kk = 0; kk < 4; ++kk) arO[kk] = *(const bf16x8*)(abase + (2*s + 5) * 2048 + kk * 512);
        }
    }

    // ---- LoRA as one extra rank-64 K chunk ----
    {
        const f32x4* p4 = (const f32x4*)part;
#pragma unroll
        for (int it = 0; it < 4; ++it) {
            int u = it * 256 + tid;            // float4 index into [64][64]
            f32x4 s = p4[u];
#pragma unroll
            for (int p = 1; p < KSPLIT; ++p) s += p4[p * 1024 + u];
            bf16x4 bv;
            bv[0] = (__bf16)s[0]; bv[1] = (__bf16)s[1];
            bv[2] = (__bf16)s[2]; bv[3] = (__bf16)s[3];
            *(bf16x4*)&t_lds[u >> 4][(u & 15) * 4] = bv;
        }
    }
#pragma unroll
    for (int it = 0; it < 4; ++it) {
        int idx = it * 256 + tid;              // 16 x 64 up' tile
        int oo = idx >> 6, cc = idx & 63;
        int l = cc >> 4, r = cc & 15;
        w_lds[0][oo][cc] = (__bf16)up[(l * OUT_DIM + n0 + oo) * R_DIM + r];
    }
    barrier_lgkm();
#pragma unroll
    for (int kk = 0; kk < 2; ++kk) {
        const int ko = kk * 32 + quad * 8;
        bf16x8 a  = *(const bf16x8*)&t_lds[wave * 16 + lrow][ko];
        bf16x8 b0 = *(const bf16x8*)&w_lds[0][lrow][ko];
        acc = __builtin_amdgcn_mfma_f32_16x16x32_bf16(a, b0, acc, 0, 0, 0);
    }

    // epilogue: C/D layout (m89): col = lane&15 (o), row = quad*4 + reg (t)
    const int o = n0 + lrow;
#pragma unroll
    for (int i = 0; i < 4; ++i) {
        const int t = wave * 16 + quad * 4 + i;
        out[t * OUT_DIM + o] = acc[i];
    }
}

// ---------------------------------------------------------------------------
extern "C" void kernel_launch(void* const* d_in, const int* in_sizes, int n_in,
                              void* d_out, int out_size, void* d_ws, size_t ws_size,
                              hipStream_t stream) {
    const float* x           = (const float*)d_in[0];
    const int*   qweight     = (const int*)d_in[1];
    const int*   zeros       = (const int*)d_in[2];
    const float* scales      = (const float*)d_in[3];
    const float* up          = (const float*)d_in[4];
    const float* down        = (const float*)d_in[5];
    const float* lora_scales = (const float*)d_in[6];
    float*  out  = (float*)d_out;
    float*  part = (float*)d_ws;                              // 128 KiB
    __bf16* xbf2 = (__bf16*)((char*)d_ws + XBF_BYTE_OFF);     // 512 KiB, frag-major

    hipLaunchKernelGGL(prep_kernel, dim3(128 + 64 * KSPLIT), dim3(256), 0, stream,
                       x, down, lora_scales, part, xbf2);
    hipLaunchKernelGGL(awq_lora_gemm_kernel, dim3(OUT_DIM / BN), dim3(256), 0, stream,
                       xbf2, qweight, zeros, scales, up, part, out);
}